// Round 3
// baseline (435.678 us; speedup 1.0000x reference)
//
#include <hip/hip_runtime.h>

#define IH 126
#define IW 126
#define HW 15876      // 126*126
#define OH 124
#define OW 124
#define OHW 15376     // 124*124

// Padded activation layout: plane [132 rows][136 cols], orig (y,x) at (y+3, x+3).
// Margins stay zero -> involution's 7x7 taps need no bounds checks.
#define PR 136
#define PROWS 132
#define PLANE (PR * PROWS)   // 17952 floats

// ---------------------------------------------------------------- zero pad bufs
__global__ __launch_bounds__(256) void zero_kernel(float* __restrict__ p, int n4)
{
  int i = blockIdx.x * 256 + threadIdx.x;
  int stride = gridDim.x * 256;
  for (; i < n4; i += stride)
    *(float4*)&p[4 * i] = make_float4(0.f, 0.f, 0.f, 0.f);
}

// ---------------------------------------------------------------- conv_in
__global__ __launch_bounds__(256) void conv_in_kernel(
    const float* __restrict__ x, const float* __restrict__ w,
    const float* __restrict__ b, float* __restrict__ y)
{
  int pix = blockIdx.x * 256 + threadIdx.x;
  if (pix >= HW) return;
  int oc = blockIdx.y;                 // wave-uniform -> weights become s_loads
  int h  = pix / IW;
  int wc = pix - h * IW;
  const float* wp = w + oc * 27;
  float acc = b[oc];
#pragma unroll
  for (int ci = 0; ci < 3; ci++)
#pragma unroll
    for (int ky = 0; ky < 3; ky++)
#pragma unroll
      for (int kx = 0; kx < 3; kx++)
        acc = fmaf(x[ci * 128 * 128 + (h + ky) * 128 + (wc + kx)],
                   wp[ci * 9 + ky * 3 + kx], acc);
  y[oc * PLANE + (h + 3) * PR + (wc + 3)] = acc;
}

// ---------------------------------------------------------------- involution A: wgen
// thread = (pixel, quarter q of the 196 span outputs). t[16] computed per
// thread (4x redundant), then 49 outputs. All weights wave-uniform s_loads,
// no LDS, no barriers. Writes w-field plane-major wf[j][HW].
__global__ __launch_bounds__(256) void wgen_kernel(
    const float* __restrict__ x, float* __restrict__ wf,
    const float* __restrict__ wr, const float* __restrict__ br,
    const float* __restrict__ gam, const float* __restrict__ bet,
    const float* __restrict__ mu, const float* __restrict__ var,
    const float* __restrict__ wspan, const float* __restrict__ bspan)
{
  int tid = threadIdx.x;
  int ln = tid & 63;
  int q = __builtin_amdgcn_readfirstlane(tid >> 6);   // 0..3, wave-uniform
  int p = blockIdx.x * 64 + ln;
  int py = p / 126;
  int px = p - py * 126;
  const float* xp = x + (py + 3) * PR + (px + 3);

  float xv[64];
#pragma unroll
  for (int ci = 0; ci < 64; ci++) xv[ci] = xp[ci * PLANE];

  float t[16];
#pragma unroll
  for (int j = 0; j < 16; j++) {
    const float* wrow = wr + j * 64;   // uniform -> s_load_dwordx16 batches
    float a = 0.f;
#pragma unroll
    for (int ci = 0; ci < 64; ci++) a = fmaf(xv[ci], wrow[ci], a);
    float s = gam[j] * rsqrtf(var[j] + 1e-5f);
    t[j] = fmaxf((a + br[j] - mu[j]) * s + bet[j], 0.f);
  }

  bool ok = (p < HW);
  const float* wsb = wspan + q * 49 * 16;
  const float* bsb = bspan + q * 49;
  float* out = wf + q * 49 * HW + p;
  for (int jj = 0; jj < 49; jj++) {
    const float* wk = wsb + jj * 16;   // uniform -> s_load_dwordx16
    float a = bsb[jj];
#pragma unroll
    for (int i = 0; i < 16; i++) a = fmaf(t[i], wk[i], a);
    if (ok) out[jj * HW] = a;
  }
}

// ---------------------------------------------------------------- involution B: einsum
// thread = (row, channel, col-pair). 49-tap dot: w-planes (coalesced float2,
// L1-shared across the block's 4 same-group channels) x padded-x (float2,
// no bounds checks thanks to zero margins). Outer ReLU fused. No LDS.
__global__ __launch_bounds__(256) void einsum_kernel(
    const float* __restrict__ x, const float* __restrict__ wf,
    float* __restrict__ y)
{
  int tid = threadIdx.x;
  int ln = tid & 63;
  int wv = __builtin_amdgcn_readfirstlane(tid >> 6);  // 0..3
  int row = blockIdx.x;                // 0..125
  int ch = blockIdx.y * 4 + wv;        // 0..63, same group within block
  int g = ch >> 4;
  if (ln >= 63) return;                // 63 col-pairs cover 126 cols
  int x0 = 2 * ln;

  const float* xpl = x + ch * PLANE;
  const float* wbase = wf + g * 49 * HW + row * 126 + x0;
  float a0 = 0.f, a1 = 0.f;
#pragma unroll
  for (int ky = 0; ky < 7; ky++) {
    // orig rows row-3..row+3 -> padded rows row..row+6; cols x0-3.. -> padded x0..
    const float* xr = xpl + (row + ky) * PR + x0;
    float xv[8];
#pragma unroll
    for (int h = 0; h < 4; h++) {
      float2 v = *(const float2*)(xr + 2 * h);    // 8B-aligned (even offsets)
      xv[2 * h] = v.x; xv[2 * h + 1] = v.y;
    }
    const float* wr_ = wbase + ky * 7 * HW;
#pragma unroll
    for (int kx = 0; kx < 7; kx++) {
      float2 w2 = *(const float2*)(wr_ + kx * HW);
      a0 = fmaf(w2.x, xv[kx], a0);
      a1 = fmaf(w2.y, xv[kx + 1], a1);
    }
  }
  float* yp = y + ch * PLANE + (row + 3) * PR + (x0 + 3);
  yp[0] = fmaxf(a0, 0.f);
  yp[1] = fmaxf(a1, 0.f);
}

// ---------------------------------------------------------------- conv_out prep
__global__ __launch_bounds__(256) void transpose_w_kernel(
    const float* __restrict__ w, float* __restrict__ wt)
{
  int i = blockIdx.x * 256 + threadIdx.x;
  if (i >= 128 * 64 * 9) return;
  int oc = i / 576;
  int rem = i - oc * 576;
  int ci = rem / 9;
  int k = rem - ci * 9;
  wt[(k * 64 + ci) * 128 + oc] = w[i];
}

// ---------------------------------------------------------------- conv_out (v3)
// Best measured variant (44.5 us). 256 threads, 4 waves x 8 oc, grid (256,4),
// 6 blocks/CU. Only change vs v3: reads the padded activation layout.
__global__ __launch_bounds__(256, 6) void conv_out_kernel(
    const float* __restrict__ x, const float* __restrict__ wt,
    const float* __restrict__ b, float* __restrict__ y)
{
  __shared__ __align__(16) float xsm[16 * 100 * 4];   // 25,600 B
  int tid = threadIdx.x;
  int bx = blockIdx.x & 15, by = blockIdx.x >> 4;
  int oy0 = by * 8, ox0 = bx * 8;

  for (int u = tid; u < 1600; u += 256) {
    int cq = u / 100;
    int pos = u - cq * 100;
    int row = pos / 10;
    int col = pos - row * 10;
    int gy = oy0 + row, gx = ox0 + col;
    float4 v = make_float4(0.f, 0.f, 0.f, 0.f);
    if (gy < IH && gx < IW) {
      const float* xp = x + cq * 4 * PLANE + (gy + 3) * PR + (gx + 3);
      v.x = xp[0]; v.y = xp[PLANE]; v.z = xp[2 * PLANE]; v.w = xp[3 * PLANE];
    }
    *(float4*)&xsm[u * 4] = v;
  }
  __syncthreads();

  int ln = tid & 63;
  int px = ln & 7, py = ln >> 3;
  int wv_ = __builtin_amdgcn_readfirstlane(tid >> 6);   // wave 0..3
  int oc8 = blockIdx.y * 32 + wv_ * 8;

  float acc[8];
#pragma unroll
  for (int j = 0; j < 8; j++) acc[j] = b[oc8 + j];

#pragma unroll
  for (int ky = 0; ky < 3; ky++) {
#pragma unroll
    for (int kx = 0; kx < 3; kx++) {
      int k = ky * 3 + kx;
      int pidx = (py + ky) * 10 + px + kx;
      const float* wp = wt + k * 64 * 128 + oc8;   // uniform -> s_loads
#pragma unroll 4
      for (int cq = 0; cq < 16; cq++) {
        float4 xv = *(const float4*)&xsm[(cq * 100 + pidx) * 4];
        const float* wq = wp + cq * 4 * 128;
#pragma unroll
        for (int j = 0; j < 8; j++) {
          acc[j] = fmaf(xv.x, wq[0 * 128 + j], acc[j]);
          acc[j] = fmaf(xv.y, wq[1 * 128 + j], acc[j]);
          acc[j] = fmaf(xv.z, wq[2 * 128 + j], acc[j]);
          acc[j] = fmaf(xv.w, wq[3 * 128 + j], acc[j]);
        }
      }
    }
  }

  int oy = oy0 + py, ox = ox0 + px;
  if (oy < OH && ox < OW) {
#pragma unroll
    for (int j = 0; j < 8; j++)
      y[(oc8 + j) * OHW + oy * OW + ox] = acc[j];
  }
}

// ---------------------------------------------------------------- launch
extern "C" void kernel_launch(void* const* d_in, const int* in_sizes, int n_in,
                              void* d_out, int out_size, void* d_ws, size_t ws_size,
                              hipStream_t stream)
{
  const float* input = (const float*)d_in[0];
  const float* ciw   = (const float*)d_in[1];
  const float* cib   = (const float*)d_in[2];
  const float* wred  = (const float*)d_in[3];
  const float* bred  = (const float*)d_in[4];
  const float* gam   = (const float*)d_in[5];
  const float* bet   = (const float*)d_in[6];
  const float* mu    = (const float*)d_in[7];
  const float* var   = (const float*)d_in[8];
  const float* wspan = (const float*)d_in[9];
  const float* bspan = (const float*)d_in[10];
  const float* cow   = (const float*)d_in[11];
  const float* cob   = (const float*)d_in[12];
  float* out = (float*)d_out;

  float* ws = (float*)d_ws;
  float* bufA   = ws;                    // 64*PLANE = 1,148,928 floats
  float* bufB   = ws + 1200000;          // 64*PLANE
  float* wfield = ws + 2400000;          // 196*HW = 3,111,696 floats
  float* wt     = ws + 5600000;          // 73,728 floats  (total ~22.7 MB)

  // zero bufA+bufB (pad margins must be 0; interiors get overwritten)
  zero_kernel<<<1024, 256, 0, stream>>>(ws, 600000);
  transpose_w_kernel<<<288, 256, 0, stream>>>(cow, wt);
  conv_in_kernel<<<dim3(63, 64), 256, 0, stream>>>(input, ciw, cib, bufA);

  float* cur = bufA; float* nxt = bufB;
  for (int i = 0; i < 6; i++) {
    wgen_kernel<<<249, 256, 0, stream>>>(cur, wfield,
        wred + i * 16 * 64, bred + i * 16, gam + i * 16, bet + i * 16,
        mu + i * 16, var + i * 16, wspan + i * 196 * 16, bspan + i * 196);
    einsum_kernel<<<dim3(126, 16), 256, 0, stream>>>(cur, wfield, nxt);
    float* t = cur; cur = nxt; nxt = t;
  }
  conv_out_kernel<<<dim3(256, 4), 256, 0, stream>>>(cur, wt, cob, out);
}

// Round 4
// 263.172 us; speedup vs baseline: 1.6555x; 1.6555x over previous
//
#include <hip/hip_runtime.h>

#define IH 126
#define IW 126
#define HW 15876      // 126*126
#define OH 124
#define OW 124
#define OHW 15376     // 124*124

// ---------------------------------------------------------------- conv_in
__global__ __launch_bounds__(256) void conv_in_kernel(
    const float* __restrict__ x, const float* __restrict__ w,
    const float* __restrict__ b, float* __restrict__ y)
{
  int pix = blockIdx.x * 256 + threadIdx.x;
  if (pix >= HW) return;
  int oc = blockIdx.y;                 // wave-uniform -> weights become s_loads
  int h  = pix / IW;
  int wc = pix - h * IW;
  const float* wp = w + oc * 27;
  float acc = b[oc];
#pragma unroll
  for (int ci = 0; ci < 3; ci++)
#pragma unroll
    for (int ky = 0; ky < 3; ky++)
#pragma unroll
      for (int kx = 0; kx < 3; kx++)
        acc = fmaf(x[ci * 128 * 128 + (h + ky) * 128 + (wc + kx)],
                   wp[ci * 9 + ky * 3 + kx], acc);
  y[oc * HW + pix] = acc;
}

// ---------------------------------------------------------------- involution v7
// Round-0 fused structure + LDS bank-conflict fixes:
//   (1) xs channel index XOR-swizzled (c ^ ((pos&7)<<3)): phase-B float4 reads
//       go 8-way-conflicted -> conflict-free; phase-D by-channel reads remain
//       free (bijective bank permutation); phase-A write 8-way (unchanged).
//   (2) wvs row stride 32 -> 36 floats: 49*36*4B = +4 banks per group ->
//       phase-D float4 reads conflict-free (was 4-way: 49*32*4B = 0 mod 32).
//   tss separate buffer (drops mid-phase-C barrier; measured neutral).
// LDS 68,864 B -> 2 blocks/CU.
#define XSW(c, pos) ((c) ^ (((pos) & 7) << 3))
#define WVP 36
__global__ __launch_bounds__(512, 4) void inv_kernel(
    const float* __restrict__ x, float* __restrict__ y,
    const float* __restrict__ wr, const float* __restrict__ br,
    const float* __restrict__ gam, const float* __restrict__ bet,
    const float* __restrict__ mu, const float* __restrict__ var,
    const float* __restrict__ wspan, const float* __restrict__ bspan)
{
  __shared__ __align__(16) float xs[140][68];   // 38,080 B; aliased by ob[64][33] in E
  __shared__ __align__(16) float wvs[196 * WVP];// 28,224 B
  __shared__ __align__(16) float tss[640];      // 2,560 B;  [32 pixels][20]
  float* ob  = &xs[0][0];                       // [64][33] alias

  int tid = threadIdx.x;
  int bx = blockIdx.x & 15, by = blockIdx.x >> 4;
  int ox0 = bx * 8, oy0 = by * 4;
  int xh0 = ox0 - 3, yh0 = oy0 - 3;

  // ---- Phase A: stage x halo (14 cols x 10 rows x 64 ch), zero-padded
  for (int idx = tid; idx < 140 * 64; idx += 512) {
    int c = idx / 140;
    int pos = idx - c * 140;
    int row = pos / 14;
    int col = pos - row * 14;
    int gy = yh0 + row, gx = xh0 + col;
    float v = 0.f;
    if (gy >= 0 && gy < IH && gx >= 0 && gx < IW)
      v = x[c * HW + gy * IW + gx];
    xs[pos][XSW(c, pos)] = v;
  }
  __syncthreads();

  int w_ = __builtin_amdgcn_readfirstlane(tid >> 6);  // wave 0..7
  int ln = tid & 63;
  int p  = ln & 31;                   // pixel 0..31 (upper 32 lanes duplicate)
  int prow = p >> 3, pcol = p & 7;
  int pc = (prow + 3) * 14 + (pcol + 3);

  // ---- Phase B: t = ReLU(BN(Wr.x)); wave w_ does cr = 2w_, 2w_+1 (uniform)
  {
    int cr0 = 2 * w_;
    const float* wa = wr + cr0 * 64;  // uniform -> s_load
    const float* wb = wa + 64;
    float a0 = 0.f, a1 = 0.f;
    int xsw = (pc & 7) << 3;          // lane's row swizzle
#pragma unroll
    for (int ci = 0; ci < 64; ci += 4) {
      int cis = ci ^ xsw;             // float4 group stays contiguous+aligned
      float4 xv = *(const float4*)&xs[pc][cis];
      a0 = fmaf(xv.x, wa[cis + 0], a0); a1 = fmaf(xv.x, wb[cis + 0], a1);
      a0 = fmaf(xv.y, wa[cis + 1], a0); a1 = fmaf(xv.y, wb[cis + 1], a1);
      a0 = fmaf(xv.z, wa[cis + 2], a0); a1 = fmaf(xv.z, wb[cis + 2], a1);
      a0 = fmaf(xv.w, wa[cis + 3], a0); a1 = fmaf(xv.w, wb[cis + 3], a1);
    }
    float s0 = gam[cr0]     * rsqrtf(var[cr0]     + 1e-5f);
    float s1 = gam[cr0 + 1] * rsqrtf(var[cr0 + 1] + 1e-5f);
    float t0 = (a0 + br[cr0]     - mu[cr0])     * s0 + bet[cr0];
    float t1 = (a1 + br[cr0 + 1] - mu[cr0 + 1]) * s1 + bet[cr0 + 1];
    if (ln < 32) {
      tss[p * 20 + cr0]     = fmaxf(t0, 0.f);
      tss[p * 20 + cr0 + 1] = fmaxf(t1, 0.f);
    }
  }
  __syncthreads();

  // ---- Phase C: span. wave w_ owns uniform pairs (g*49+k) = w_ + 8j.
  {
    float tv[16];
#pragma unroll
    for (int i = 0; i < 4; i++) {
      float4 t4 = *(const float4*)&tss[p * 20 + 4 * i];
      tv[4 * i] = t4.x; tv[4 * i + 1] = t4.y;
      tv[4 * i + 2] = t4.z; tv[4 * i + 3] = t4.w;
    }
    for (int j = 0; j < 25; j++) {
      int pair = w_ + 8 * j;           // wave-uniform
      if (pair < 196) {
        const float* wk = wspan + pair * 16;   // uniform -> s_load_dwordx16
        float a = bspan[pair];
#pragma unroll
        for (int i = 0; i < 16; i++) a = fmaf(tv[i], wk[i], a);
        if (ln < 32) wvs[pair * WVP + pcol * 4 + prow] = a;
      }
    }
  }
  __syncthreads();

  // ---- Phase D: einsum. wave = output column w_, lane = channel.
  float acc0 = 0.f, acc1 = 0.f, acc2 = 0.f, acc3 = 0.f;
  {
    int c = ln;
    int g = ln >> 4;
    float xw[4][7];
#pragma unroll
    for (int r = 0; r < 4; r++)
#pragma unroll
      for (int kx = 0; kx < 7; kx++) {
        int pos = r * 14 + w_ + kx;            // wave-uniform
        xw[r][kx] = xs[pos][XSW(c, pos)];      // 2 lanes/bank: conflict-free
      }
#pragma unroll
    for (int ky = 0; ky < 7; ky++) {
      if (ky > 0) {
#pragma unroll
        for (int r = 0; r < 3; r++)
#pragma unroll
          for (int kx = 0; kx < 7; kx++) xw[r][kx] = xw[r + 1][kx];
#pragma unroll
        for (int kx = 0; kx < 7; kx++) {
          int pos = (ky + 3) * 14 + w_ + kx;
          xw[3][kx] = xs[pos][XSW(c, pos)];
        }
      }
#pragma unroll
      for (int kx = 0; kx < 7; kx++) {
        int k = ky * 7 + kx;
        float4 w4 = *(const float4*)&wvs[(g * 49 + k) * WVP + w_ * 4];
        acc0 = fmaf(w4.x, xw[0][kx], acc0);
        acc1 = fmaf(w4.y, xw[1][kx], acc1);
        acc2 = fmaf(w4.z, xw[2][kx], acc2);
        acc3 = fmaf(w4.w, xw[3][kx], acc3);
      }
    }
  }
  __syncthreads();                     // xs reads done; safe to alias with ob

  // ---- Phase E: transpose via LDS, coalesced store (+outer ReLU)
  {
    int c = ln;
    ob[c * 33 + 0 * 8 + w_] = fmaxf(acc0, 0.f);
    ob[c * 33 + 1 * 8 + w_] = fmaxf(acc1, 0.f);
    ob[c * 33 + 2 * 8 + w_] = fmaxf(acc2, 0.f);
    ob[c * 33 + 3 * 8 + w_] = fmaxf(acc3, 0.f);
  }
  __syncthreads();
  for (int j = tid; j < 2048; j += 512) {
    int c2 = j >> 5, pp = j & 31;
    int pr = pp >> 3, pc2 = pp & 7;
    int gy = oy0 + pr, gx = ox0 + pc2;
    if (gy < IH && gx < IW)
      y[c2 * HW + gy * IW + gx] = ob[c2 * 33 + pp];
  }
}

// ---------------------------------------------------------------- conv_out prep
__global__ __launch_bounds__(256) void transpose_w_kernel(
    const float* __restrict__ w, float* __restrict__ wt)
{
  int i = blockIdx.x * 256 + threadIdx.x;
  if (i >= 128 * 64 * 9) return;
  int oc = i / 576;
  int rem = i - oc * 576;
  int ci = rem / 9;
  int k = rem - ci * 9;
  wt[(k * 64 + ci) * 128 + oc] = w[i];
}

// ---------------------------------------------------------------- conv_out v3 (best measured: 44.5 us)
__global__ __launch_bounds__(256, 6) void conv_out_kernel(
    const float* __restrict__ x, const float* __restrict__ wt,
    const float* __restrict__ b, float* __restrict__ y)
{
  __shared__ __align__(16) float xsm[16 * 100 * 4];   // 25,600 B
  int tid = threadIdx.x;
  int bx = blockIdx.x & 15, by = blockIdx.x >> 4;
  int oy0 = by * 8, ox0 = bx * 8;

  for (int u = tid; u < 1600; u += 256) {
    int cq = u / 100;
    int pos = u - cq * 100;
    int row = pos / 10;
    int col = pos - row * 10;
    int gy = oy0 + row, gx = ox0 + col;
    float4 v = make_float4(0.f, 0.f, 0.f, 0.f);
    if (gy < IH && gx < IW) {
      const float* xp = x + cq * 4 * HW + gy * IW + gx;
      v.x = xp[0]; v.y = xp[HW]; v.z = xp[2 * HW]; v.w = xp[3 * HW];
    }
    *(float4*)&xsm[u * 4] = v;
  }
  __syncthreads();

  int ln = tid & 63;
  int px = ln & 7, py = ln >> 3;
  int wv_ = __builtin_amdgcn_readfirstlane(tid >> 6);   // wave 0..3
  int oc8 = blockIdx.y * 32 + wv_ * 8;

  float acc[8];
#pragma unroll
  for (int j = 0; j < 8; j++) acc[j] = b[oc8 + j];

#pragma unroll
  for (int ky = 0; ky < 3; ky++) {
#pragma unroll
    for (int kx = 0; kx < 3; kx++) {
      int k = ky * 3 + kx;
      int pidx = (py + ky) * 10 + px + kx;
      const float* wp = wt + k * 64 * 128 + oc8;   // uniform -> s_loads
#pragma unroll 4
      for (int cq = 0; cq < 16; cq++) {
        float4 xv = *(const float4*)&xsm[(cq * 100 + pidx) * 4];
        const float* wq = wp + cq * 4 * 128;
#pragma unroll
        for (int j = 0; j < 8; j++) {
          acc[j] = fmaf(xv.x, wq[0 * 128 + j], acc[j]);
          acc[j] = fmaf(xv.y, wq[1 * 128 + j], acc[j]);
          acc[j] = fmaf(xv.z, wq[2 * 128 + j], acc[j]);
          acc[j] = fmaf(xv.w, wq[3 * 128 + j], acc[j]);
        }
      }
    }
  }

  int oy = oy0 + py, ox = ox0 + px;
  if (oy < OH && ox < OW) {
#pragma unroll
    for (int j = 0; j < 8; j++)
      y[(oc8 + j) * OHW + oy * OW + ox] = acc[j];
  }
}

// ---------------------------------------------------------------- launch
extern "C" void kernel_launch(void* const* d_in, const int* in_sizes, int n_in,
                              void* d_out, int out_size, void* d_ws, size_t ws_size,
                              hipStream_t stream)
{
  const float* input = (const float*)d_in[0];
  const float* ciw   = (const float*)d_in[1];
  const float* cib   = (const float*)d_in[2];
  const float* wred  = (const float*)d_in[3];
  const float* bred  = (const float*)d_in[4];
  const float* gam   = (const float*)d_in[5];
  const float* bet   = (const float*)d_in[6];
  const float* mu    = (const float*)d_in[7];
  const float* var   = (const float*)d_in[8];
  const float* wspan = (const float*)d_in[9];
  const float* bspan = (const float*)d_in[10];
  const float* cow   = (const float*)d_in[11];
  const float* cob   = (const float*)d_in[12];
  float* out = (float*)d_out;

  float* bufA = (float*)d_ws;                 // 64*126*126 = 1,016,064 floats
  float* bufB = bufA + (1 << 20);             // @ 4 MiB
  float* wt   = bufA + (1 << 21);             // @ 8 MiB, 73,728 floats

  transpose_w_kernel<<<288, 256, 0, stream>>>(cow, wt);
  conv_in_kernel<<<dim3(63, 64), 256, 0, stream>>>(input, ciw, cib, bufA);

  float* cur = bufA; float* nxt = bufB;
  for (int i = 0; i < 6; i++) {
    inv_kernel<<<512, 512, 0, stream>>>(cur, nxt,
        wred + i * 16 * 64, bred + i * 16, gam + i * 16, bet + i * 16,
        mu + i * 16, var + i * 16, wspan + i * 196 * 16, bspan + i * 196);
    float* t = cur; cur = nxt; nxt = t;
  }
  conv_out_kernel<<<dim3(256, 4), 256, 0, stream>>>(cur, wt, cob, out);
}